// Round 6
// baseline (16.225 us; speedup 1.0000x reference)
//
#include <hip/hip_runtime.h>

// out[b,o] = sum_k sbar[b,k] * Meff[k,o]
//   sbar[b,k] = mean_n exp(-(r_bn - 3k/7)^2),  r = ||p - centroid|| (+1e-12 under sqrt)
//   Meff = W1a@W1b@W2a@W2b / sqrt(8*6*6*6), with 1/128 point-mean AND
//   wk = exp(-(3k/7)^2) folded in.  exp(-(r-ck)^2) = wk * e^{-r^2} * (e^{6r/7})^k.
//
// v6: instruction-coalesced loads + LDS bounce at full occupancy.
//   tile = 2 batches (3 KB) per wave; 3x global_load_dwordx4, per-instruction
//   fully contiguous (16 cache lines/instr). Wave-private LDS staging (3 KB),
//   in-order DS pipe -> no barrier, just an lgkmcnt fence. Each lane then owns
//   12 contiguous floats = 4 whole points. Batch = 32-lane half-wave:
//   reductions = 4x DPP row_ror + 1x ds_swizzle(xor 16).
//   16384 waves = 2 generations/CU -> gen-2 loads overlap gen-1 compute.

template <int N>
__device__ __forceinline__ float ror16(float v) {
    return __int_as_float(__builtin_amdgcn_update_dpp(
        0, __float_as_int(v), 0x120 | N, 0xF, 0xF, true));
}
__device__ __forceinline__ float rowsum16(float v) {
    v += ror16<1>(v);
    v += ror16<2>(v);
    v += ror16<4>(v);
    v += ror16<8>(v);
    return v;   // all 16 lanes of the row hold the row total
}
__device__ __forceinline__ float xor16_add(float v) {
    // ds_swizzle BitMode xor 16 (and=0x1F): exchanges row pairs within each
    // 32-lane half; combined with rowsum16 gives the 32-lane group total.
    return v + __int_as_float(__builtin_amdgcn_ds_swizzle(__float_as_int(v), 0x401F));
}

__global__ __launch_bounds__(256, 8) void sph_fused(
    const float* __restrict__ pos,
    const float* __restrict__ W1a, const float* __restrict__ W1b,
    const float* __restrict__ W2a, const float* __restrict__ W2b,
    float* __restrict__ out, int nBatch)
{
    __shared__ float BBs[36];
    __shared__ float CCs[36];
    __shared__ float MMs[48];
    __shared__ float4 stage[4][192];   // 3 KB per wave

    const int t = threadIdx.x;

    // ---- effective 8x6 matrix, wk folded into row k (tiny, once per block) ----
    if (t < 36) {
        const int c = t / 6, o = t - 6 * c;
        float s = 0.f;
        #pragma unroll
        for (int j = 0; j < 6; ++j) s += W2a[c * 6 + j] * W2b[j * 6 + o];
        BBs[t] = s;
    }
    __syncthreads();
    if (t < 36) {
        const int c = t / 6, o = t - 6 * c;
        float s = 0.f;
        #pragma unroll
        for (int j = 0; j < 6; ++j) s += W1b[c * 6 + j] * BBs[j * 6 + o];
        CCs[t] = s;
    }
    __syncthreads();
    if (t < 48) {
        const int k = t / 6, o = t - 6 * k;
        float s = 0.f;
        #pragma unroll
        for (int c = 0; c < 6; ++c) s += W1a[k * 6 + c] * CCs[c * 6 + o];
        const float WKtab[8] = {1.0f, 0.83220583f, 0.47965235f, 0.19146295f,
                                0.05293049f, 0.01013418f, 0.00134381f, 1.2340980e-4f};
        MMs[t] = s * WKtab[k] * (0.024056261216234408f / 128.0f); // 1/sqrt(1728)/128
    }
    __syncthreads();   // last block-wide barrier before any early return

    const int lane = t & 63;
    const int w    = t >> 6;

    const int nTiles = (nBatch + 1) >> 1;        // 2 batches per tile
    const int tile = blockIdx.x * 4 + w;
    if (tile >= nTiles) return;

    // ---- 3 coalesced wave-loads -> wave-private LDS ----
    const float4* __restrict__ p4 = reinterpret_cast<const float4*>(pos);
    const int lastC = nBatch * 96 - 1;           // last valid float4 chunk
    #pragma unroll
    for (int j = 0; j < 3; ++j) {
        int gc = tile * 192 + 64 * j + lane;     // per-instr contiguous 1 KB
        if (gc > lastC) gc = lastC;              // tail clamp; stores guarded
        stage[w][64 * j + lane] = p4[gc];
    }
    // same-wave DS ops complete in order; fence so the compiler keeps order.
    asm volatile("s_waitcnt lgkmcnt(0)" ::: "memory");

    // ---- each lane reads its 12 contiguous floats = 4 whole points ----
    union { float4 q[3]; float f[12]; } u;
    #pragma unroll
    for (int s = 0; s < 3; ++s) u.q[s] = stage[w][3 * lane + s];

    // ---- centroid over the 32-lane batch group ----
    float sx = u.f[0] + u.f[3] + u.f[6] + u.f[9];
    float sy = u.f[1] + u.f[4] + u.f[7] + u.f[10];
    float sz = u.f[2] + u.f[5] + u.f[8] + u.f[11];
    sx = xor16_add(rowsum16(sx));
    sy = xor16_add(rowsum16(sy));
    sz = xor16_add(rowsum16(sz));
    const float mx = sx * (1.f / 128.f), my = sy * (1.f / 128.f), mz = sz * (1.f / 128.f);

    // ---- RBFs: 2 exps + 1 sqrt per point; wk deferred to the matrix ----
    float a0 = 0.f, a1 = 0.f, a2 = 0.f, a3 = 0.f,
          a4 = 0.f, a5 = 0.f, a6 = 0.f, a7 = 0.f;
    #pragma unroll
    for (int i = 0; i < 4; ++i) {
        const float dx = u.f[3 * i + 0] - mx;
        const float dy = u.f[3 * i + 1] - my;
        const float dz = u.f[3 * i + 2] - mz;
        const float r2 = fmaf(dx, dx, fmaf(dy, dy, fmaf(dz, dz, 1e-12f)));
        float r;
        asm("v_sqrt_f32 %0, %1" : "=v"(r) : "v"(r2));
        const float E0 = __expf(-r2);                 // e^{-r^2}
        const float Bf = __expf(r * (6.0f / 7.0f));   // e^{6r/7}
        float p = E0;
        a0 += E0;
        p *= Bf; a1 += p;
        p *= Bf; a2 += p;
        p *= Bf; a3 += p;
        p *= Bf; a4 += p;
        p *= Bf; a5 += p;
        p *= Bf; a6 += p;
        p *= Bf; a7 += p;
    }
    a0 = xor16_add(rowsum16(a0)); a1 = xor16_add(rowsum16(a1));
    a2 = xor16_add(rowsum16(a2)); a3 = xor16_add(rowsum16(a3));
    a4 = xor16_add(rowsum16(a4)); a5 = xor16_add(rowsum16(a5));
    a6 = xor16_add(rowsum16(a6)); a7 = xor16_add(rowsum16(a7));

    // ---- 8x6 matvec ----
    const int idx = lane & 31;
    const int col = (idx < 6) ? idx : 0;
    float o_ = a0 * MMs[0 * 6 + col];
    o_ = fmaf(a1, MMs[1 * 6 + col], o_);
    o_ = fmaf(a2, MMs[2 * 6 + col], o_);
    o_ = fmaf(a3, MMs[3 * 6 + col], o_);
    o_ = fmaf(a4, MMs[4 * 6 + col], o_);
    o_ = fmaf(a5, MMs[5 * 6 + col], o_);
    o_ = fmaf(a6, MMs[6 * 6 + col], o_);
    o_ = fmaf(a7, MMs[7 * 6 + col], o_);

    const int batch = tile * 2 + (lane >> 5);
    if (idx < 6 && batch < nBatch) out[batch * 6 + idx] = o_;
}

extern "C" void kernel_launch(void* const* d_in, const int* in_sizes, int n_in,
                              void* d_out, int out_size, void* d_ws, size_t ws_size,
                              hipStream_t stream) {
    const float* pos = (const float*)d_in[0];
    const float* W1a = (const float*)d_in[1];
    const float* W1b = (const float*)d_in[2];
    const float* W2a = (const float*)d_in[5];
    const float* W2b = (const float*)d_in[6];
    float* out = (float*)d_out;

    const int nBatch = in_sizes[0] / 384;        // 32768 for the bench shape
    const int nTiles = (nBatch + 1) / 2;         // 2 batches per wave
    const int grid = (nTiles + 3) / 4;           // 4 waves per block

    sph_fused<<<dim3(grid), dim3(256), 0, stream>>>(pos, W1a, W1b, W2a, W2b, out, nBatch);
}